// Round 17
// baseline (1549.301 us; speedup 1.0000x reference)
//
#include <hip/hip_runtime.h>

typedef unsigned short u16;
typedef unsigned int u32;
typedef unsigned long long ull;
typedef __attribute__((ext_vector_type(8))) short bf16x8;
typedef __attribute__((ext_vector_type(4))) float f32x4;
typedef __attribute__((ext_vector_type(4))) unsigned u32x4;

#define B_   128
#define T_   512
#define NOBS 256
#define H_   512
#define G4   2048
#define NACT 32
#define M_   (B_*T_)   // 65536
#define GR   8         // batch islands
#define ROWS 16        // batch rows per island
#define UN   16        // hidden units per WG
#define ZW   66        // zs row stride (floats), padded: conflict-free
#define SENT 0x7FC07FC0u   // {NaN,NaN} bf16 pair: impossible for h in (-1,1)

__device__ __forceinline__ float b2f(u16 s) {
  union { unsigned u; float f; } v; v.u = ((unsigned)s) << 16; return v.f;
}
__device__ __forceinline__ u16 f2b(float f) {
  union { float f; unsigned u; } v; v.f = f;
  unsigned r = v.u + 0x7FFFu + ((v.u >> 16) & 1u);
  return (u16)(r >> 16);
}
__device__ __forceinline__ float sigm(float x) { return 1.f/(1.f+__expf(-x)); }
__device__ __forceinline__ float tanh_f(float x) { return 1.f - 2.f/(1.f+__expf(2.f*x)); }

__device__ __forceinline__ void gld16(const void* g, void* ldsbase) {
#if __has_builtin(__builtin_amdgcn_global_load_lds)
  __builtin_amdgcn_global_load_lds((const __attribute__((address_space(1))) void*)g,
                                   (__attribute__((address_space(3))) void*)ldsbase, 16, 0, 0);
#else
  ((float4*)ldsbase)[threadIdx.x & 63] = *(const float4*)g;
#endif
}

// ---------------- prep kernels ----------------
// obs (B,T,NOBS) f32 -> obsT (T,B,NOBS) bf16
__global__ void k_cvt_obsT(const float* __restrict__ in, u16* __restrict__ out) {
  const long i = (long)blockIdx.x*blockDim.x + threadIdx.x;   // 8-elem chunk id
  const int k8 = (int)(i & (NOBS/8 - 1));
  const long row = i >> 5;                 // t*B + b
  const int t = (int)(row >> 7), b = (int)(row & (B_-1));
  const float* src = in + ((long)b*T_ + t)*NOBS + k8*8;
  ushort2 o[4];
  #pragma unroll
  for (int q = 0; q < 4; ++q) {
    o[q].x = f2b(src[q*2]);
    o[q].y = f2b(src[q*2+1]);
  }
  *(ushort2*)&out[i*8+0] = o[0]; *(ushort2*)&out[i*8+2] = o[1];
  *(ushort2*)&out[i*8+4] = o[2]; *(ushort2*)&out[i*8+6] = o[3];
}

// h planes init: plane 0 = h0 packed pairs; planes 1..7 = SENT. Grid 1024x256.
__global__ void k_inith(const float* __restrict__ h0, u16* __restrict__ hp) {
  const int i = blockIdx.x*256 + threadIdx.x;     // u32 index across 8 planes
  const int plane = i >> 15, off = i & 32767;     // 32768 u32 per plane
  u32 v;
  if (plane == 0) {
    const int row = off >> 8, p = off & 255;
    v = (unsigned)f2b(h0[row*H_ + 2*p]) | ((unsigned)f2b(h0[row*H_ + 2*p + 1]) << 16);
  } else {
    v = SENT;
  }
  ((u32*)hp)[i] = v;
}

// out (C,R) bf16 <- in (R,C) f32
__global__ void k_transpose(const float* __restrict__ in, u16* __restrict__ out, int R, int C) {
  int i = blockIdx.x*blockDim.x + threadIdx.x;
  if (i < R*C) {
    int c = i / R, r = i - c*R;
    out[i] = f2b(in[r*C + c]);
  }
}

// ---------------- GEMM: C(M,N) = A(M,K) @ BT(N,K)^T ----------------
template<int EPI>
__global__ __launch_bounds__(256) void k_gemm_bt(const u16* __restrict__ A, const u16* __restrict__ BT,
                                                 u16* __restrict__ C, const float* __restrict__ bias,
                                                 int M, int N, int K)
{
  __shared__ u16 As[128*64];
  __shared__ u16 Bs[128*64];
  const int tid = threadIdx.x, wv = tid >> 6, lane = tid & 63;
  const int ntile = N >> 7;
  const int tm = blockIdx.x / ntile, tn = blockIdx.x - tm*ntile;
  const int wr = wv >> 1, wc = wv & 1;
  f32x4 acc[4][4];
  for (int m=0;m<4;++m) for (int n=0;n<4;++n) acc[m][n] = (f32x4){0.f,0.f,0.f,0.f};
  const long abase = (long)tm*128, bbase = (long)tn*128;
  const int kit = K >> 6;
  for (int kt = 0; kt < kit; ++kt) {
    const int k0 = kt << 6;
    #pragma unroll
    for (int q = 0; q < 4; ++q) {
      int off = (wv*4+q)*1024 + lane*16;
      int row = off >> 7, colb = off & 127;
      gld16((const char*)A  + ((abase+row)*K + k0)*2 + colb, (char*)As + (wv*4+q)*1024);
      gld16((const char*)BT + ((bbase+row)*K + k0)*2 + colb, (char*)Bs + (wv*4+q)*1024);
    }
    asm volatile("s_waitcnt vmcnt(0)" ::: "memory");
    __syncthreads();
    const int kg = (lane >> 4) * 8;
    #pragma unroll
    for (int kk = 0; kk < 64; kk += 32) {
      bf16x8 af[4], bfr[4];
      #pragma unroll
      for (int m = 0; m < 4; ++m)
        af[m] = *(const bf16x8*)(As + (wr*64 + m*16 + (lane&15))*64 + kk + kg);
      #pragma unroll
      for (int n = 0; n < 4; ++n)
        bfr[n] = *(const bf16x8*)(Bs + (wc*64 + n*16 + (lane&15))*64 + kk + kg);
      #pragma unroll
      for (int m = 0; m < 4; ++m)
        #pragma unroll
        for (int n = 0; n < 4; ++n)
          acc[m][n] = __builtin_amdgcn_mfma_f32_16x16x32_bf16(af[m], bfr[n], acc[m][n], 0, 0, 0);
    }
    __syncthreads();
  }
  const int rq = (lane >> 4) * 4, cl = lane & 15;
  #pragma unroll
  for (int n = 0; n < 4; ++n) {
    const int coln = (int)bbase + wc*64 + n*16 + cl;
    const float bv = (EPI == 1) ? bias[coln] : 0.f;
    #pragma unroll
    for (int m = 0; m < 4; ++m) {
      const long rowb = abase + wr*64 + m*16 + rq;
      #pragma unroll
      for (int q = 0; q < 4; ++q) {
        float v = acc[m][n][q];
        if (EPI == 1) v = fmaxf(v + bv, 0.f);
        C[(rowb+q)*(long)N + coln] = f2b(v);
      }
    }
  }
}

// ---------------- persistent LSTM scan, v14: sentinel protocol + throttled poll --------
// r15 verbatim except ONE change: the retry loop sleeps ~384cy between rounds.
// r16's counters showed ~19 poll rounds/step = 58 TB/s of redundant L2-miss
// traffic saturating the LLC fabric — the polls were congesting the publishes
// they wait on. Backoff cuts poll traffic ~4x; detection overshoot ~100cy/step.
__global__ __launch_bounds__(256, 1) void k_scan(
    const u16* __restrict__ obsT, const u16* __restrict__ WxT, const u16* __restrict__ WhT,
    const float* __restrict__ bvec, const float* __restrict__ c0f,
    u16* __restrict__ hp,
    u16* __restrict__ ys, float* __restrict__ outh, float* __restrict__ outc)
{
  __shared__ u16 Bw[96*64*8];      // weight slice [kg 0..95][col 0..63][8] (96 KB)
  __shared__ float zs[2][16*ZW];   // split-K partials
  __shared__ float cst[256];       // cell state slice
  __shared__ float bsl[64];        // bias slice

  const int tid = threadIdx.x, wv = tid >> 6, lane = tid & 63;
  const int wg = blockIdx.x, isl = wg & (GR-1), cg = wg >> 3;
  const int rb0 = isl*ROWS, S0 = cg*UN;

  const int kh = wv >> 1, ch = wv & 1;
  const int C0 = ch*32;
  const int lq = lane >> 4, l15 = lane & 15;
  const int arow = rb0 + l15;

  // one-time: weight slice into LDS (r3/r15-verified pattern).
  for (int idx = tid; idx < 96*64; idx += 256) {
    const int kg = idx >> 6, col = idx & 63;
    const long jrow = (long)((col >> 4)*H_ + S0 + (col & 15));
    const u16* src = (kg < 32) ? (WxT + jrow*NOBS + kg*8)
                               : (WhT + jrow*H_ + (long)(kg-32)*8);
    *(bf16x8*)(Bw + (long)idx*8) = *(const bf16x8*)src;
  }
  cst[tid] = c0f[(rb0 + (tid >> 4))*H_ + S0 + (tid & 15)];
  if (tid < 64) bsl[tid] = bvec[(tid >> 4)*H_ + S0 + (tid & 15)];
  __syncthreads();

  const long fofs = (long)arow*H_ + kh*256 + lq*8;   // bulk fragment offset (u16)
  const int ldsC = (C0 + l15)*8;                     // B-fragment LDS col offset

  // obs fragments for t=0 (prefetched one step ahead thereafter)
  bf16x8 ax[4];
  {
    const u16* Ax = obsT + (long)arow*NOBS + kh*128 + lq*8;
    #pragma unroll
    for (int ks = 0; ks < 4; ++ks) ax[ks] = *(const bf16x8*)(Ax + ks*32);
  }

  for (int t = 0; t < T_; ++t) {
    f32x4 acc0 = {0.f,0.f,0.f,0.f}, acc1 = {0.f,0.f,0.f,0.f};
    union { u32x4 u; bf16x8 v; } hf[8];
    const u16* haddr = hp + ((long)(t & 7) << 16) + fofs;

    // pre-drain: completes last step's publish/sentinel/ys stores (the
    // sentinel-drain safety edge) and the obs prefetch. After this, the only
    // outstanding VMEM ops are the sample loads below -> exact counting.
    asm volatile("s_waitcnt vmcnt(0)" ::: "memory");

    // issue the first poll sample (8 x 16B from plane t&7)
    #pragma unroll
    for (int ks = 0; ks < 8; ++ks)
      asm volatile("global_load_dwordx4 %0, %1, off offset:%2 sc0 sc1"
                   : "=v"(hf[ks].u) : "v"(haddr), "i"(ks*64));

    // phase X: obs_t @ Wx — pure ds_read + MFMA, overlaps the sample's L3 RTT
    #pragma unroll
    for (int ks = 0; ks < 4; ++ks) {
      const u16* bp = Bw + (kh*16 + ks*4 + lq)*512 + ldsC;
      bf16x8 b0 = *(const bf16x8*)bp;
      bf16x8 b1 = *(const bf16x8*)(bp + 128);
      acc0 = __builtin_amdgcn_mfma_f32_16x16x32_bf16(ax[ks], b0, acc0, 0, 0, 0);
      acc1 = __builtin_amdgcn_mfma_f32_16x16x32_bf16(ax[ks], b1, acc1, 0, 0, 0);
    }
    __builtin_amdgcn_sched_barrier(0);

    // wait + validate; retry (with ~384cy backoff) while any word == SENT.
    // Backoff kills the 19-round/step poll flood (58 TB/s fabric congestion).
    {
      asm volatile("s_waitcnt vmcnt(0)" ::: "memory");
      __builtin_amdgcn_sched_barrier(0);
      unsigned ready = 1u;
      #pragma unroll
      for (int ks = 0; ks < 8; ++ks)
        #pragma unroll
        for (int j = 0; j < 4; ++j)
          ready &= (hf[ks].u[j] != SENT) ? 1u : 0u;
      if (!__all((int)ready)) {
        int spin = 1 << 12;                  // bailout: fail visibly, never hang
        for (;;) {
          __builtin_amdgcn_s_sleep(6);       // ~384cy backoff: decongest fabric
          #pragma unroll
          for (int ks = 0; ks < 8; ++ks)
            asm volatile("global_load_dwordx4 %0, %1, off offset:%2 sc0 sc1"
                         : "=v"(hf[ks].u) : "v"(haddr), "i"(ks*64));
          asm volatile("s_waitcnt vmcnt(0)" ::: "memory");
          __builtin_amdgcn_sched_barrier(0);
          unsigned rdy = 1u;
          #pragma unroll
          for (int ks = 0; ks < 8; ++ks)
            #pragma unroll
            for (int j = 0; j < 4; ++j)
              rdy &= (hf[ks].u[j] != SENT) ? 1u : 0u;
          if (__all((int)rdy)) break;
          if (--spin == 0) break;
        }
      }
    }

    // obs prefetch for t+1 (plain loads; drained by next step's pre-drain)
    bf16x8 axn[4];
    {
      const int tn = (t+1 < T_) ? t+1 : t;
      const u16* Axn = obsT + ((long)tn*B_ + arow)*NOBS + kh*128 + lq*8;
      #pragma unroll
      for (int ks = 0; ks < 4; ++ks) axn[ks] = *(const bf16x8*)(Axn + ks*32);
    }

    // phase H: h @ Wh — B-fragments from LDS
    #pragma unroll
    for (int ks = 0; ks < 8; ++ks) {
      const u16* bp = Bw + (32 + kh*32 + ks*4 + lq)*512 + ldsC;
      bf16x8 b0 = *(const bf16x8*)bp;
      bf16x8 b1 = *(const bf16x8*)(bp + 128);
      acc0 = __builtin_amdgcn_mfma_f32_16x16x32_bf16(hf[ks].v, b0, acc0, 0, 0, 0);
      acc1 = __builtin_amdgcn_mfma_f32_16x16x32_bf16(hf[ks].v, b1, acc1, 0, 0, 0);
    }
    #pragma unroll
    for (int ks = 0; ks < 4; ++ks) ax[ks] = axn[ks];

    // split-K partials to LDS  (D layout: col=lane&15, row=(lane>>4)*4+q)
    {
      const int zr0 = lq*4, zc = C0 + l15;
      #pragma unroll
      for (int q = 0; q < 4; ++q) {
        zs[kh][(zr0+q)*ZW + zc]      = acc0[q];
        zs[kh][(zr0+q)*ZW + zc + 16] = acc1[q];
      }
    }
    __syncthreads();

    // epilogue: 128 threads, 2 units each. PUBLISH = fire-and-forget data store.
    // No drain, no barrier, no flag. Sentinel pre-cleans plane (t+5)&7.
    if (tid < 128) {
      const int rr = tid >> 3, pp = tid & 7;
      float hv2[2], cn2[2];
      #pragma unroll
      for (int u = 0; u < 2; ++u) {
        const int sl = 2*pp + u;
        const float* z0 = &zs[0][rr*ZW];
        const float* z1 = &zs[1][rr*ZW];
        const float zi = z0[sl]    + z1[sl]    + bsl[sl];
        const float zf = z0[16+sl] + z1[16+sl] + bsl[16+sl];
        const float zg = z0[32+sl] + z1[32+sl] + bsl[32+sl];
        const float zo = z0[48+sl] + z1[48+sl] + bsl[48+sl];
        const float cv = cst[rr*16 + sl];
        const float cn = sigm(zf)*cv + sigm(zi)*tanh_f(zg);
        hv2[u] = sigm(zo)*tanh_f(cn);
        cn2[u] = cn;
        cst[rr*16 + sl] = cn;
      }
      const unsigned h01 = (unsigned)f2b(hv2[0]) | ((unsigned)f2b(hv2[1]) << 16);
      const int bq = rb0 + rr;
      const long wofs = (long)bq*H_ + S0 + 2*pp;
      if (t < T_-1)
        __hip_atomic_store((u32*)(hp + ((long)((t+1) & 7) << 16) + wofs), h01,
                           __ATOMIC_RELAXED, __HIP_MEMORY_SCOPE_AGENT);
      __hip_atomic_store((u32*)(hp + ((long)((t+5) & 7) << 16) + wofs), SENT,
                         __ATOMIC_RELAXED, __HIP_MEMORY_SCOPE_AGENT);
      *(u32*)(ys + ((long)bq*T_ + t)*H_ + S0 + 2*pp) = h01;
      if (t == T_-1) {
        outh[bq*H_ + S0 + 2*pp]     = hv2[0];
        outh[bq*H_ + S0 + 2*pp + 1] = hv2[1];
        outc[bq*H_ + S0 + 2*pp]     = cn2[0];
        outc[bq*H_ + S0 + 2*pp + 1] = cn2[1];
      }
    }
    // no trailing barrier: poll(t+1) passing implies own WG's epilogue published,
    // which is program-ordered after its zs(t) reads => zs WAR ordered (as r14).
  }
}

// ---------------- head ----------------
__global__ __launch_bounds__(256) void k_head(const u16* __restrict__ X, const u16* __restrict__ WoT,
    const float* __restrict__ bo, const float* __restrict__ amin, const float* __restrict__ amax,
    float* __restrict__ out)
{
  __shared__ u16 Ws[NACT*H_];
  __shared__ float sc[3*NACT];
  const int tid = threadIdx.x;
  #pragma unroll
  for (int q = 0; q < 8; ++q)
    ((float4*)Ws)[q*256 + tid] = ((const float4*)WoT)[q*256 + tid];
  if (tid < NACT) { sc[tid] = bo[tid]; sc[NACT+tid] = amin[tid]; sc[2*NACT+tid] = amax[tid]; }
  __syncthreads();
  const long r = (long)blockIdx.x*64 + (tid >> 2);
  const int c0 = (tid & 3)*8;
  float acc[8];
  #pragma unroll
  for (int c = 0; c < 8; ++c) acc[c] = 0.f;
  const u16* Arow = X + r*H_;
  for (int kc = 0; kc < H_/8; ++kc) {
    bf16x8 a = *(const bf16x8*)(Arow + kc*8);
    float av[8];
    #pragma unroll
    for (int j = 0; j < 8; ++j) av[j] = b2f((u16)a[j]);
    #pragma unroll
    for (int c = 0; c < 8; ++c) {
      bf16x8 w = *(const bf16x8*)(Ws + (c0+c)*H_ + kc*8);
      #pragma unroll
      for (int j = 0; j < 8; ++j) acc[c] += av[j] * b2f((u16)w[j]);
    }
  }
  #pragma unroll
  for (int c = 0; c < 8; ++c) {
    const int cc = c0 + c;
    const float y = acc[c] + sc[cc];
    const float tv = tanhf(y);
    out[r*NACT + cc] = 0.5f*(tv*(sc[2*NACT+cc]-sc[NACT+cc]) + (sc[2*NACT+cc]+sc[NACT+cc]));
  }
}

extern "C" void kernel_launch(void* const* d_in, const int* in_sizes, int n_in,
                              void* d_out, int out_size, void* d_ws, size_t ws_size,
                              hipStream_t stream) {
  const float* obs = (const float*)d_in[0];
  const float* h0  = (const float*)d_in[1];
  const float* c0  = (const float*)d_in[2];
  const float* Wx  = (const float*)d_in[3];
  const float* Wh  = (const float*)d_in[4];
  const float* bb  = (const float*)d_in[5];
  const float* W1  = (const float*)d_in[6];
  const float* b1  = (const float*)d_in[7];
  const float* W2  = (const float*)d_in[8];
  const float* b2  = (const float*)d_in[9];
  const float* Wo  = (const float*)d_in[10];
  const float* bo  = (const float*)d_in[11];
  const float* amin= (const float*)d_in[12];
  const float* amax= (const float*)d_in[13];

  char* ws = (char*)d_ws;
  // workspace layout (bytes), within the proven footprint. hp (8 planes x 128KiB
  // = 1 MiB) lives at the head of the dead t1 region (r14-proven aliasing).
  u16* obsT  = (u16*)(ws + 0);                 // (T,B,NOBS) bf16, 32 MiB
  u16* ys    = (u16*)(ws + 33554432);          // (B,T,H) bf16, 64 MiB
  u16* t1    = (u16*)(ws + 100663296);         // 64 MiB
  u16* t2    = (u16*)(ws + 33554432);          // alias ys (dead after W1-GEMM)
  u16* hp    = (u16*)(ws + 100663296);         // 8 h planes, 1 MiB (in dead t1)
  u16* WxT   = (u16*)(ws + 167772160);         // (G4, NOBS)  1 MiB
  u16* WhT   = (u16*)(ws + 168820736);         // (G4, H)     2 MiB
  u16* W1T   = (u16*)(ws + 170917888);         // 0.5 MiB
  u16* W2T   = (u16*)(ws + 171442176);         // 0.5 MiB
  u16* WoT   = (u16*)(ws + 171966464);         // 64 KiB

  float* outA = (float*)d_out;
  float* outh = outA + (long)M_*NACT;
  float* outc = outh + B_*H_;

  k_cvt_obsT<<<M_*NOBS/8/256, 256, 0, stream>>>(obs, obsT);
  k_inith<<<1024, 256, 0, stream>>>(h0, hp);          // plane 0 = h0; 1..7 = SENT
  k_transpose<<<2048, 256, 0, stream>>>(Wx, WxT, NOBS, G4);
  k_transpose<<<4096, 256, 0, stream>>>(Wh, WhT, H_, G4);
  k_transpose<<<1024, 256, 0, stream>>>(W1, W1T, H_, H_);
  k_transpose<<<1024, 256, 0, stream>>>(W2, W2T, H_, H_);
  k_transpose<<<64,   256, 0, stream>>>(Wo, WoT, H_, NACT);

  // persistent scan: 256 co-resident WGs (1/CU), throttled sentinel exchange
  k_scan<<<256, 256, 0, stream>>>(obsT, WxT, WhT, bb, c0, hp, ys, outh, outc);

  // MLP head
  k_gemm_bt<1><<<(M_/128)*(H_/128), 256, 0, stream>>>(ys, W1T, t1, b1, M_, H_, H_);
  k_gemm_bt<1><<<(M_/128)*(H_/128), 256, 0, stream>>>(t1, W2T, t2, b2, M_, H_, H_);
  k_head<<<M_/64, 256, 0, stream>>>(t2, WoT, bo, amin, amax, outA);
}

// Round 18
// 1472.437 us; speedup vs baseline: 1.0522x; 1.0522x over previous
//
#include <hip/hip_runtime.h>

typedef unsigned short u16;
typedef unsigned int u32;
typedef unsigned long long ull;
typedef __attribute__((ext_vector_type(8))) short bf16x8;
typedef __attribute__((ext_vector_type(4))) float f32x4;
typedef __attribute__((ext_vector_type(4))) unsigned u32x4;

#define B_   128
#define T_   512
#define NOBS 256
#define H_   512
#define G4   2048
#define NACT 32
#define M_   (B_*T_)   // 65536
#define GR   8         // batch islands
#define ROWS 16        // batch rows per island
#define UN   16        // hidden units per WG
#define ZW   66        // zs row stride (floats), padded: conflict-free
#define SENT 0x7FC07FC0u   // {NaN,NaN} bf16 pair: impossible for h in (-1,1)

__device__ __forceinline__ float b2f(u16 s) {
  union { unsigned u; float f; } v; v.u = ((unsigned)s) << 16; return v.f;
}
__device__ __forceinline__ u16 f2b(float f) {
  union { float f; unsigned u; } v; v.f = f;
  unsigned r = v.u + 0x7FFFu + ((v.u >> 16) & 1u);
  return (u16)(r >> 16);
}
__device__ __forceinline__ float sigm(float x) { return 1.f/(1.f+__expf(-x)); }
__device__ __forceinline__ float tanh_f(float x) { return 1.f - 2.f/(1.f+__expf(2.f*x)); }

__device__ __forceinline__ void gld16(const void* g, void* ldsbase) {
#if __has_builtin(__builtin_amdgcn_global_load_lds)
  __builtin_amdgcn_global_load_lds((const __attribute__((address_space(1))) void*)g,
                                   (__attribute__((address_space(3))) void*)ldsbase, 16, 0, 0);
#else
  ((float4*)ldsbase)[threadIdx.x & 63] = *(const float4*)g;
#endif
}

// ---------------- prep kernels ----------------
// obs (B,T,NOBS) f32 -> obsT (T,B,NOBS) bf16
__global__ void k_cvt_obsT(const float* __restrict__ in, u16* __restrict__ out) {
  const long i = (long)blockIdx.x*blockDim.x + threadIdx.x;   // 8-elem chunk id
  const int k8 = (int)(i & (NOBS/8 - 1));
  const long row = i >> 5;                 // t*B + b
  const int t = (int)(row >> 7), b = (int)(row & (B_-1));
  const float* src = in + ((long)b*T_ + t)*NOBS + k8*8;
  ushort2 o[4];
  #pragma unroll
  for (int q = 0; q < 4; ++q) {
    o[q].x = f2b(src[q*2]);
    o[q].y = f2b(src[q*2+1]);
  }
  *(ushort2*)&out[i*8+0] = o[0]; *(ushort2*)&out[i*8+2] = o[1];
  *(ushort2*)&out[i*8+4] = o[2]; *(ushort2*)&out[i*8+6] = o[3];
}

// h planes init: plane 0 = h0 packed pairs; planes 1..7 = SENT. Grid 1024x256.
__global__ void k_inith(const float* __restrict__ h0, u16* __restrict__ hp) {
  const int i = blockIdx.x*256 + threadIdx.x;     // u32 index across 8 planes
  const int plane = i >> 15, off = i & 32767;     // 32768 u32 per plane
  u32 v;
  if (plane == 0) {
    const int row = off >> 8, p = off & 255;
    v = (unsigned)f2b(h0[row*H_ + 2*p]) | ((unsigned)f2b(h0[row*H_ + 2*p + 1]) << 16);
  } else {
    v = SENT;
  }
  ((u32*)hp)[i] = v;
}

// fused weight transposes: all five out(C,R) <- in(R,C) in ONE launch.
// ranges (elements): WxT 524288 | WhT 1048576 | W1T 262144 | W2T 262144 | WoT 16384
__global__ void k_prep_wT(const float* __restrict__ Wx, const float* __restrict__ Wh,
                          const float* __restrict__ W1, const float* __restrict__ W2,
                          const float* __restrict__ Wo,
                          u16* __restrict__ WxT, u16* __restrict__ WhT,
                          u16* __restrict__ W1T, u16* __restrict__ W2T,
                          u16* __restrict__ WoT) {
  int i = blockIdx.x*256 + threadIdx.x;
  const float* in; u16* out; int R, C;
  if (i < 524288)        { in = Wx; out = WxT; R = NOBS; C = G4; }
  else if (i < 1572864)  { i -= 524288;  in = Wh; out = WhT; R = H_; C = G4; }
  else if (i < 1835008)  { i -= 1572864; in = W1; out = W1T; R = H_; C = H_; }
  else if (i < 2097152)  { i -= 1835008; in = W2; out = W2T; R = H_; C = H_; }
  else                   { i -= 2097152; in = Wo; out = WoT; R = H_; C = NACT; }
  const int c = i / R, r = i - c*R;
  out[i] = f2b(in[r*C + c]);
}

// ---------------- GEMM: C(M,N) = A(M,K) @ BT(N,K)^T ----------------
template<int EPI>
__global__ __launch_bounds__(256) void k_gemm_bt(const u16* __restrict__ A, const u16* __restrict__ BT,
                                                 u16* __restrict__ C, const float* __restrict__ bias,
                                                 int M, int N, int K)
{
  __shared__ u16 As[128*64];
  __shared__ u16 Bs[128*64];
  const int tid = threadIdx.x, wv = tid >> 6, lane = tid & 63;
  const int ntile = N >> 7;
  const int tm = blockIdx.x / ntile, tn = blockIdx.x - tm*ntile;
  const int wr = wv >> 1, wc = wv & 1;
  f32x4 acc[4][4];
  for (int m=0;m<4;++m) for (int n=0;n<4;++n) acc[m][n] = (f32x4){0.f,0.f,0.f,0.f};
  const long abase = (long)tm*128, bbase = (long)tn*128;
  const int kit = K >> 6;
  for (int kt = 0; kt < kit; ++kt) {
    const int k0 = kt << 6;
    #pragma unroll
    for (int q = 0; q < 4; ++q) {
      int off = (wv*4+q)*1024 + lane*16;
      int row = off >> 7, colb = off & 127;
      gld16((const char*)A  + ((abase+row)*K + k0)*2 + colb, (char*)As + (wv*4+q)*1024);
      gld16((const char*)BT + ((bbase+row)*K + k0)*2 + colb, (char*)Bs + (wv*4+q)*1024);
    }
    asm volatile("s_waitcnt vmcnt(0)" ::: "memory");
    __syncthreads();
    const int kg = (lane >> 4) * 8;
    #pragma unroll
    for (int kk = 0; kk < 64; kk += 32) {
      bf16x8 af[4], bfr[4];
      #pragma unroll
      for (int m = 0; m < 4; ++m)
        af[m] = *(const bf16x8*)(As + (wr*64 + m*16 + (lane&15))*64 + kk + kg);
      #pragma unroll
      for (int n = 0; n < 4; ++n)
        bfr[n] = *(const bf16x8*)(Bs + (wc*64 + n*16 + (lane&15))*64 + kk + kg);
      #pragma unroll
      for (int m = 0; m < 4; ++m)
        #pragma unroll
        for (int n = 0; n < 4; ++n)
          acc[m][n] = __builtin_amdgcn_mfma_f32_16x16x32_bf16(af[m], bfr[n], acc[m][n], 0, 0, 0);
    }
    __syncthreads();
  }
  const int rq = (lane >> 4) * 4, cl = lane & 15;
  #pragma unroll
  for (int n = 0; n < 4; ++n) {
    const int coln = (int)bbase + wc*64 + n*16 + cl;
    const float bv = (EPI == 1) ? bias[coln] : 0.f;
    #pragma unroll
    for (int m = 0; m < 4; ++m) {
      const long rowb = abase + wr*64 + m*16 + rq;
      #pragma unroll
      for (int q = 0; q < 4; ++q) {
        float v = acc[m][n][q];
        if (EPI == 1) v = fmaxf(v + bv, 0.f);
        C[(rowb+q)*(long)N + coln] = f2b(v);
      }
    }
  }
}

// ---------------- persistent LSTM scan, v12 (r15 exact — proven 3x @ ~1350us) ----------
__global__ __launch_bounds__(256, 1) void k_scan(
    const u16* __restrict__ obsT, const u16* __restrict__ WxT, const u16* __restrict__ WhT,
    const float* __restrict__ bvec, const float* __restrict__ c0f,
    u16* __restrict__ hp,
    u16* __restrict__ ys, float* __restrict__ outh, float* __restrict__ outc)
{
  __shared__ u16 Bw[96*64*8];      // weight slice [kg 0..95][col 0..63][8] (96 KB)
  __shared__ float zs[2][16*ZW];   // split-K partials
  __shared__ float cst[256];       // cell state slice
  __shared__ float bsl[64];        // bias slice

  const int tid = threadIdx.x, wv = tid >> 6, lane = tid & 63;
  const int wg = blockIdx.x, isl = wg & (GR-1), cg = wg >> 3;
  const int rb0 = isl*ROWS, S0 = cg*UN;

  const int kh = wv >> 1, ch = wv & 1;
  const int C0 = ch*32;
  const int lq = lane >> 4, l15 = lane & 15;
  const int arow = rb0 + l15;

  // one-time: weight slice into LDS (r3/r15-verified pattern).
  for (int idx = tid; idx < 96*64; idx += 256) {
    const int kg = idx >> 6, col = idx & 63;
    const long jrow = (long)((col >> 4)*H_ + S0 + (col & 15));
    const u16* src = (kg < 32) ? (WxT + jrow*NOBS + kg*8)
                               : (WhT + jrow*H_ + (long)(kg-32)*8);
    *(bf16x8*)(Bw + (long)idx*8) = *(const bf16x8*)src;
  }
  cst[tid] = c0f[(rb0 + (tid >> 4))*H_ + S0 + (tid & 15)];
  if (tid < 64) bsl[tid] = bvec[(tid >> 4)*H_ + S0 + (tid & 15)];
  __syncthreads();

  const long fofs = (long)arow*H_ + kh*256 + lq*8;   // bulk fragment offset (u16)
  const int ldsC = (C0 + l15)*8;                     // B-fragment LDS col offset

  // obs fragments for t=0 (prefetched one step ahead thereafter)
  bf16x8 ax[4];
  {
    const u16* Ax = obsT + (long)arow*NOBS + kh*128 + lq*8;
    #pragma unroll
    for (int ks = 0; ks < 4; ++ks) ax[ks] = *(const bf16x8*)(Ax + ks*32);
  }

  for (int t = 0; t < T_; ++t) {
    f32x4 acc0 = {0.f,0.f,0.f,0.f}, acc1 = {0.f,0.f,0.f,0.f};
    union { u32x4 u; bf16x8 v; } hf[8];
    const u16* haddr = hp + ((long)(t & 7) << 16) + fofs;

    // pre-drain: completes last step's publish/sentinel/ys stores (the
    // sentinel-drain safety edge) and the obs prefetch.
    asm volatile("s_waitcnt vmcnt(0)" ::: "memory");

    // issue the first poll sample (8 x 16B from plane t&7)
    #pragma unroll
    for (int ks = 0; ks < 8; ++ks)
      asm volatile("global_load_dwordx4 %0, %1, off offset:%2 sc0 sc1"
                   : "=v"(hf[ks].u) : "v"(haddr), "i"(ks*64));

    // phase X: obs_t @ Wx — pure ds_read + MFMA, overlaps the sample's RTT
    #pragma unroll
    for (int ks = 0; ks < 4; ++ks) {
      const u16* bp = Bw + (kh*16 + ks*4 + lq)*512 + ldsC;
      bf16x8 b0 = *(const bf16x8*)bp;
      bf16x8 b1 = *(const bf16x8*)(bp + 128);
      acc0 = __builtin_amdgcn_mfma_f32_16x16x32_bf16(ax[ks], b0, acc0, 0, 0, 0);
      acc1 = __builtin_amdgcn_mfma_f32_16x16x32_bf16(ax[ks], b1, acc1, 0, 0, 0);
    }
    __builtin_amdgcn_sched_barrier(0);

    // wait + validate; retry while any word == SENT (tearing => retry)
    {
      asm volatile("s_waitcnt vmcnt(0)" ::: "memory");
      __builtin_amdgcn_sched_barrier(0);
      unsigned ready = 1u;
      #pragma unroll
      for (int ks = 0; ks < 8; ++ks)
        #pragma unroll
        for (int j = 0; j < 4; ++j)
          ready &= (hf[ks].u[j] != SENT) ? 1u : 0u;
      if (!__all((int)ready)) {
        int spin = 1 << 12;                  // bailout: fail visibly, never hang
        for (;;) {
          #pragma unroll
          for (int ks = 0; ks < 8; ++ks)
            asm volatile("global_load_dwordx4 %0, %1, off offset:%2 sc0 sc1"
                         : "=v"(hf[ks].u) : "v"(haddr), "i"(ks*64));
          asm volatile("s_waitcnt vmcnt(0)" ::: "memory");
          __builtin_amdgcn_sched_barrier(0);
          unsigned rdy = 1u;
          #pragma unroll
          for (int ks = 0; ks < 8; ++ks)
            #pragma unroll
            for (int j = 0; j < 4; ++j)
              rdy &= (hf[ks].u[j] != SENT) ? 1u : 0u;
          if (__all((int)rdy)) break;
          if (--spin == 0) break;
        }
      }
    }

    // obs prefetch for t+1 (plain loads; drained by next step's pre-drain)
    bf16x8 axn[4];
    {
      const int tn = (t+1 < T_) ? t+1 : t;
      const u16* Axn = obsT + ((long)tn*B_ + arow)*NOBS + kh*128 + lq*8;
      #pragma unroll
      for (int ks = 0; ks < 4; ++ks) axn[ks] = *(const bf16x8*)(Axn + ks*32);
    }

    // phase H: h @ Wh — B-fragments from LDS
    #pragma unroll
    for (int ks = 0; ks < 8; ++ks) {
      const u16* bp = Bw + (32 + kh*32 + ks*4 + lq)*512 + ldsC;
      bf16x8 b0 = *(const bf16x8*)bp;
      bf16x8 b1 = *(const bf16x8*)(bp + 128);
      acc0 = __builtin_amdgcn_mfma_f32_16x16x32_bf16(hf[ks].v, b0, acc0, 0, 0, 0);
      acc1 = __builtin_amdgcn_mfma_f32_16x16x32_bf16(hf[ks].v, b1, acc1, 0, 0, 0);
    }
    #pragma unroll
    for (int ks = 0; ks < 4; ++ks) ax[ks] = axn[ks];

    // split-K partials to LDS  (D layout: col=lane&15, row=(lane>>4)*4+q)
    {
      const int zr0 = lq*4, zc = C0 + l15;
      #pragma unroll
      for (int q = 0; q < 4; ++q) {
        zs[kh][(zr0+q)*ZW + zc]      = acc0[q];
        zs[kh][(zr0+q)*ZW + zc + 16] = acc1[q];
      }
    }
    __syncthreads();

    // epilogue: 128 threads, 2 units each. PUBLISH = fire-and-forget data store.
    if (tid < 128) {
      const int rr = tid >> 3, pp = tid & 7;
      float hv2[2], cn2[2];
      #pragma unroll
      for (int u = 0; u < 2; ++u) {
        const int sl = 2*pp + u;
        const float* z0 = &zs[0][rr*ZW];
        const float* z1 = &zs[1][rr*ZW];
        const float zi = z0[sl]    + z1[sl]    + bsl[sl];
        const float zf = z0[16+sl] + z1[16+sl] + bsl[16+sl];
        const float zg = z0[32+sl] + z1[32+sl] + bsl[32+sl];
        const float zo = z0[48+sl] + z1[48+sl] + bsl[48+sl];
        const float cv = cst[rr*16 + sl];
        const float cn = sigm(zf)*cv + sigm(zi)*tanh_f(zg);
        hv2[u] = sigm(zo)*tanh_f(cn);
        cn2[u] = cn;
        cst[rr*16 + sl] = cn;
      }
      const unsigned h01 = (unsigned)f2b(hv2[0]) | ((unsigned)f2b(hv2[1]) << 16);
      const int bq = rb0 + rr;
      const long wofs = (long)bq*H_ + S0 + 2*pp;
      if (t < T_-1)
        __hip_atomic_store((u32*)(hp + ((long)((t+1) & 7) << 16) + wofs), h01,
                           __ATOMIC_RELAXED, __HIP_MEMORY_SCOPE_AGENT);
      __hip_atomic_store((u32*)(hp + ((long)((t+5) & 7) << 16) + wofs), SENT,
                         __ATOMIC_RELAXED, __HIP_MEMORY_SCOPE_AGENT);
      *(u32*)(ys + ((long)bq*T_ + t)*H_ + S0 + 2*pp) = h01;
      if (t == T_-1) {
        outh[bq*H_ + S0 + 2*pp]     = hv2[0];
        outh[bq*H_ + S0 + 2*pp + 1] = hv2[1];
        outc[bq*H_ + S0 + 2*pp]     = cn2[0];
        outc[bq*H_ + S0 + 2*pp + 1] = cn2[1];
      }
    }
  }
}

// ---------------- head (MFMA): out = 0.5*(tanh(X@WoT^T+bo)*(amax-amin)+(amax+amin)) ----
// wave = 16 rows x 32 cols; block = 4 waves = 64 rows; grid 1024. WoT staged in
// LDS with +8 u16 row padding (stride 520 -> 1040B) to break 16-way conflicts.
#define WSW 520
__global__ __launch_bounds__(256) void k_head_mfma(const u16* __restrict__ X,
    const u16* __restrict__ WoT, const float* __restrict__ bo,
    const float* __restrict__ amin, const float* __restrict__ amax,
    float* __restrict__ out)
{
  __shared__ u16 Ws[NACT*WSW];     // 32 rows x 520 (padded)
  const int tid = threadIdx.x, wv = tid >> 6, lane = tid & 63;
  // stage: 2048 16B chunks (32 rows x 64 chunks), 8 per thread
  #pragma unroll
  for (int q = 0; q < 8; ++q) {
    const int chunk = q*256 + tid, r = chunk >> 6, c = chunk & 63;
    *(float4*)(Ws + r*WSW + c*8) = ((const float4*)WoT)[chunk];
  }
  __syncthreads();
  const int lq = lane >> 4, l15 = lane & 15;
  const long rb = (long)blockIdx.x*64 + wv*16;
  const u16* Ab = X + (rb + l15)*H_ + lq*8;
  f32x4 acc0 = {0.f,0.f,0.f,0.f}, acc1 = {0.f,0.f,0.f,0.f};
  #pragma unroll
  for (int ks = 0; ks < 16; ++ks) {
    bf16x8 a  = *(const bf16x8*)(Ab + ks*32);
    bf16x8 b0 = *(const bf16x8*)(Ws + l15*WSW + ks*32 + lq*8);
    bf16x8 b1 = *(const bf16x8*)(Ws + (16+l15)*WSW + ks*32 + lq*8);
    acc0 = __builtin_amdgcn_mfma_f32_16x16x32_bf16(a, b0, acc0, 0, 0, 0);
    acc1 = __builtin_amdgcn_mfma_f32_16x16x32_bf16(a, b1, acc1, 0, 0, 0);
  }
  // D layout: col=lane&15, row=(lane>>4)*4+q
  const int c0 = l15, c1 = 16 + l15;
  const float bo0 = bo[c0], bo1 = bo[c1];
  const float a0 = amin[c0], A0 = amax[c0], a1 = amin[c1], A1 = amax[c1];
  #pragma unroll
  for (int q = 0; q < 4; ++q) {
    const long r = rb + lq*4 + q;
    const float y0 = tanh_f(acc0[q] + bo0), y1 = tanh_f(acc1[q] + bo1);
    out[r*NACT + c0] = 0.5f*(y0*(A0 - a0) + (A0 + a0));
    out[r*NACT + c1] = 0.5f*(y1*(A1 - a1) + (A1 + a1));
  }
}

extern "C" void kernel_launch(void* const* d_in, const int* in_sizes, int n_in,
                              void* d_out, int out_size, void* d_ws, size_t ws_size,
                              hipStream_t stream) {
  const float* obs = (const float*)d_in[0];
  const float* h0  = (const float*)d_in[1];
  const float* c0  = (const float*)d_in[2];
  const float* Wx  = (const float*)d_in[3];
  const float* Wh  = (const float*)d_in[4];
  const float* bb  = (const float*)d_in[5];
  const float* W1  = (const float*)d_in[6];
  const float* b1  = (const float*)d_in[7];
  const float* W2  = (const float*)d_in[8];
  const float* b2  = (const float*)d_in[9];
  const float* Wo  = (const float*)d_in[10];
  const float* bo  = (const float*)d_in[11];
  const float* amin= (const float*)d_in[12];
  const float* amax= (const float*)d_in[13];

  char* ws = (char*)d_ws;
  // workspace layout (bytes), within the proven footprint. hp (8 planes x 128KiB
  // = 1 MiB) lives at the head of the dead t1 region (r14-proven aliasing).
  u16* obsT  = (u16*)(ws + 0);                 // (T,B,NOBS) bf16, 32 MiB
  u16* ys    = (u16*)(ws + 33554432);          // (B,T,H) bf16, 64 MiB
  u16* t1    = (u16*)(ws + 100663296);         // 64 MiB
  u16* t2    = (u16*)(ws + 33554432);          // alias ys (dead after W1-GEMM)
  u16* hp    = (u16*)(ws + 100663296);         // 8 h planes, 1 MiB (in dead t1)
  u16* WxT   = (u16*)(ws + 167772160);         // (G4, NOBS)  1 MiB
  u16* WhT   = (u16*)(ws + 168820736);         // (G4, H)     2 MiB
  u16* W1T   = (u16*)(ws + 170917888);         // 0.5 MiB
  u16* W2T   = (u16*)(ws + 171442176);         // 0.5 MiB
  u16* WoT   = (u16*)(ws + 171966464);         // 64 KiB

  float* outA = (float*)d_out;
  float* outh = outA + (long)M_*NACT;
  float* outc = outh + B_*H_;

  k_cvt_obsT<<<M_*NOBS/8/256, 256, 0, stream>>>(obs, obsT);
  k_inith<<<1024, 256, 0, stream>>>(h0, hp);          // plane 0 = h0; 1..7 = SENT
  k_prep_wT<<<8256, 256, 0, stream>>>(Wx, Wh, W1, W2, Wo, WxT, WhT, W1T, W2T, WoT);

  // persistent scan: 256 co-resident WGs (1/CU), sentinel-in-data h exchange
  k_scan<<<256, 256, 0, stream>>>(obsT, WxT, WhT, bb, c0, hp, ys, outh, outc);

  // MLP head
  k_gemm_bt<1><<<(M_/128)*(H_/128), 256, 0, stream>>>(ys, W1T, t1, b1, M_, H_, H_);
  k_gemm_bt<1><<<(M_/128)*(H_/128), 256, 0, stream>>>(t1, W2T, t2, b2, M_, H_, H_);
  k_head_mfma<<<M_/64, 256, 0, stream>>>(t2, WoT, bo, amin, amax, outA);
}